// Round 5
// baseline (738.000 us; speedup 1.0000x reference)
//
#include <hip/hip_runtime.h>

// ---- problem constants ----
#define KK 8192
#define NN 28672
#define MM 32
#define GRP 128
#define NBLK 32                 // n-rows per block
#define NBLOCKS (NN / NBLK)     // 896
#define TILEK 128               // k per tile (= one quant group)
#define WTILES 16               // tiles per wave: K / (4 waves * 128)

// HARNESS DTYPE CONTRACT: universe is {bf16, f32, int32}; reference fp16
// tensors arrive as FLOAT32 (this explained rounds 1-3: fp16/bf16 misreads
// of f32 buffers -> 4.28e37 / NaN signatures).
typedef __bf16 bf16;
typedef bf16  bf16x8 __attribute__((ext_vector_type(8)));
typedef float floatx4 __attribute__((ext_vector_type(4)));

// One block: 4 waves, 32 n-rows, full M=32. Wave wv handles k in [wv*2048, wv*2048+2048).
// Per wave per 128-k tile: 4 k-steps x 2 n-tiles x 2 m-tiles of mfma 16x16x32 bf16.
// k-bijection (same map for A and B frags, so the contraction is exact for any
// HW (lane-group, elem)->k order): k = s*32 + lg*8 + elem, lg = lane>>4.
__global__ __launch_bounds__(256, 4) void qgemm_kernel(
    const float* __restrict__ A, const int* __restrict__ qw,
    const float* __restrict__ scales, const float* __restrict__ zeros,
    const float* __restrict__ bias, float* __restrict__ out) {
  __shared__ float red[3][64][16];   // 12 KB: waves 1-3 park partials

  const int tid = threadIdx.x;
  const int wv  = tid >> 6;
  const int l   = tid & 63;
  const int lr  = l & 15;   // A-row / B-col within 16x16 tile
  const int lg  = l >> 4;   // k-chunk selector
  const int n0  = blockIdx.x * NBLK;

  const int kb_e = wv * 2048;   // element k base for this wave
  const int kb_i = wv * 1024;   // int32 k base (2 weights per int32)

  floatx4 acc[2][2];
#pragma unroll
  for (int a = 0; a < 2; ++a)
#pragma unroll
    for (int b = 0; b < 2; ++b) acc[a][b] = (floatx4){0.f, 0.f, 0.f, 0.f};

  for (int t = 0; t < WTILES; ++t) {
    const int g = wv * WTILES + t;   // quant group index (one group per 128-k tile)

    // scales/zeros for the 2 n-tiles (rows n0+lr, n0+16+lr), f32
    const float s0 = scales[(n0 + lr) * 64 + g];
    const float z0 = zeros [(n0 + lr) * 64 + g];
    const float s1 = scales[(n0 + 16 + lr) * 64 + g];
    const float z1 = zeros [(n0 + 16 + lr) * 64 + g];
    // w = (q - z)*s = (128+q)*s + c0, with 128+q exact in f32, c0 = -(128+z)*s
    const float c1[2] = {s0, s1};
    const float c0[2] = {-(128.f + z0) * s0, -(128.f + z1) * s1};

    // A fragments: f32 loads (A = 1 MB -> L2-resident), convert to bf16 in regs.
    bf16x8 af[2][4];
#pragma unroll
    for (int s = 0; s < 4; ++s) {
#pragma unroll
      for (int mt = 0; mt < 2; ++mt) {
        const float* ap = A + (mt * 16 + lr) * KK + kb_e + t * TILEK + s * 32 + lg * 8;
        const float4 fa = *(const float4*)(ap);
        const float4 fb = *(const float4*)(ap + 4);
        bf16x8 f;
        f[0] = (bf16)fa.x; f[1] = (bf16)fa.y; f[2] = (bf16)fa.z; f[3] = (bf16)fa.w;
        f[4] = (bf16)fb.x; f[5] = (bf16)fb.y; f[6] = (bf16)fb.z; f[7] = (bf16)fb.w;
        af[mt][s] = f;
      }
    }

#pragma unroll
    for (int s = 0; s < 4; ++s) {
#pragma unroll
      for (int nt = 0; nt < 2; ++nt) {
        // this lane's B fragment bytes: 4 int32 = 8 consecutive-k weights
        const uint4 v = *(const uint4*)(qw + (n0 + nt * 16 + lr) * 4096 + kb_i + t * 64 + (s * 4 + lg) * 4);
        bf16x8 bfr;
#pragma unroll
        for (int i = 0; i < 4; ++i) {
          const unsigned q = ((const unsigned*)&v)[i];
          // biased f32: 0x43000000 | (nib<<16) == 128+nib exactly; low nibble = even k
          const float lo = __builtin_bit_cast(float, 0x43000000u | ((q & 0x0Fu) << 16));
          const float hi = __builtin_bit_cast(float, 0x43000000u | ((q & 0xF0u) << 12));
          bfr[2 * i]     = (bf16)__builtin_fmaf(lo, c1[nt], c0[nt]);
          bfr[2 * i + 1] = (bf16)__builtin_fmaf(hi, c1[nt], c0[nt]);
        }
#pragma unroll
        for (int mt = 0; mt < 2; ++mt)
          acc[mt][nt] = __builtin_amdgcn_mfma_f32_16x16x32_bf16(af[mt][s], bfr, acc[mt][nt], 0, 0, 0);
      }
    }
  }

  // ---- cross-wave k-reduction through LDS ----
  if (wv > 0) {
#pragma unroll
    for (int mt = 0; mt < 2; ++mt)
#pragma unroll
      for (int nt = 0; nt < 2; ++nt)
#pragma unroll
        for (int r = 0; r < 4; ++r)
          red[wv - 1][l][mt * 8 + nt * 4 + r] = acc[mt][nt][r];
  }
  __syncthreads();
  if (wv == 0) {
    // C/D layout (verified m89/m91): reg r of lane l -> C[row=(l>>4)*4+r][col=l&15]
#pragma unroll
    for (int mt = 0; mt < 2; ++mt)
#pragma unroll
      for (int nt = 0; nt < 2; ++nt)
#pragma unroll
        for (int r = 0; r < 4; ++r) {
          float v = acc[mt][nt][r];
#pragma unroll
          for (int w2 = 0; w2 < 3; ++w2) v += red[w2][l][mt * 8 + nt * 4 + r];
          const int m = mt * 16 + lg * 4 + r;
          const int n = n0 + nt * 16 + lr;
          out[m * NN + n] = v + bias[n];
        }
  }
}

extern "C" void kernel_launch(void* const* d_in, const int* in_sizes, int n_in,
                              void* d_out, int out_size, void* d_ws, size_t ws_size,
                              hipStream_t stream) {
  const float* A    = (const float*)d_in[0];
  const int*   qw   = (const int*)d_in[1];
  const float* sc   = (const float*)d_in[2];
  const float* zr   = (const float*)d_in[3];
  const float* bias = (const float*)d_in[4];
  float*       out  = (float*)d_out;

  qgemm_kernel<<<dim3(NBLOCKS), dim3(256), 0, stream>>>(A, qw, sc, zr, bias, out);
}

// Round 7
// 698.470 us; speedup vs baseline: 1.0566x; 1.0566x over previous
//
#include <hip/hip_runtime.h>

// ---- problem constants ----
#define KK 8192
#define NN 28672
#define MM 32
#define NBLK 16                 // n-rows per block
#define NBLOCKS (NN / NBLK)     // 1792 = exactly 7 blocks/CU on 256 CUs
#define WTILES 16               // 128-k tiles per wave: K / (4 waves * 128)

// HARNESS DTYPE CONTRACT: universe is {bf16, f32, int32}; reference fp16
// tensors arrive as FLOAT32. Verified round 5 (PASS, absmax 0.125).
typedef __bf16 bf16;
typedef bf16  bf16x8 __attribute__((ext_vector_type(8)));
typedef float floatx4 __attribute__((ext_vector_type(4)));

// A (32x8192 f32, 1MB) -> bf16 (0.5MB) once per launch into d_ws.
// 32768 threads x 8 elems. Removes per-tile cvt work + halves A L2 traffic.
__global__ __launch_bounds__(256) void aconv_kernel(const float* __restrict__ A,
                                                    bf16* __restrict__ Ab) {
  const int i = (blockIdx.x * 256 + threadIdx.x) * 8;
  const float4 fa = *(const float4*)(A + i);
  const float4 fb = *(const float4*)(A + i + 4);
  bf16x8 o;
  o[0] = (bf16)fa.x; o[1] = (bf16)fa.y; o[2] = (bf16)fa.z; o[3] = (bf16)fa.w;
  o[4] = (bf16)fb.x; o[5] = (bf16)fb.y; o[6] = (bf16)fb.z; o[7] = (bf16)fb.w;
  *(bf16x8*)(Ab + i) = o;
}

// One block: 4 waves, 16 n-rows, full M=32. Wave wv owns k in [wv*2048, +2048).
// Per 128-k tile: 4 k-steps x 2 m-tiles of mfma 16x16x32 bf16 (8 MFMA/tile).
// k-bijection (same map for A and B frags -> contraction exact for any HW
// (lane-group, elem)->k order): k = s*32 + lg*8 + elem, lg = lane>>4.
__global__ __launch_bounds__(256, 4) void qgemm_kernel(
    const bf16* __restrict__ Ab, const int* __restrict__ qw,
    const float* __restrict__ scales, const float* __restrict__ zeros,
    const float* __restrict__ bias, float* __restrict__ out) {
  __shared__ float red[3][64][8];   // 6 KB: waves 1-3 park partials

  const int tid = threadIdx.x;
  const int wv  = tid >> 6;
  const int l   = tid & 63;
  const int lr  = l & 15;   // B-row (n) selector / A-row selector with mt
  const int lg  = l >> 4;   // k-chunk selector
  const int n0  = blockIdx.x * NBLK;

  const int kb_e = wv * 2048;   // element k base for this wave
  const int kb_i = wv * 1024;   // int32 k base (2 weights per int32)
  const int gb   = wv * WTILES; // first quant group of this wave's k-range

  // 16 consecutive groups' scales/zeros for row n0+lr -> float4 vector loads
  const float4* sp = (const float4*)(scales + (n0 + lr) * 64 + gb);
  const float4* zp = (const float4*)(zeros  + (n0 + lr) * 64 + gb);

  floatx4 acc[2];
  acc[0] = (floatx4){0.f, 0.f, 0.f, 0.f};
  acc[1] = (floatx4){0.f, 0.f, 0.f, 0.f};

#pragma unroll
  for (int q = 0; q < 4; ++q) {
    const float4 sv = sp[q];
    const float4 zv = zp[q];
#pragma unroll
    for (int u = 0; u < 4; ++u) {     // tile t = q*4+u, fully static
      const int t = q * 4 + u;
      const float c1 = (u == 0) ? sv.x : (u == 1) ? sv.y : (u == 2) ? sv.z : sv.w;
      const float zz = (u == 0) ? zv.x : (u == 1) ? zv.y : (u == 2) ? zv.z : zv.w;
      // w = (q4 - z)*s = (128+q4)*s + c0, 128+q4 exact in f32, c0 = -(128+z)*s
      const float c0 = -(128.f + zz) * c1;

#pragma unroll
      for (int s = 0; s < 4; ++s) {
        // this lane's B fragment: 4 int32 = 8 consecutive-k weights (16B load)
        const uint4 v = *(const uint4*)(qw + (n0 + lr) * 4096 + kb_i + t * 64 + (s * 4 + lg) * 4);
        bf16x8 bfr;
#pragma unroll
        for (int i = 0; i < 4; ++i) {
          const unsigned qd = ((const unsigned*)&v)[i];
          // biased f32: 0x43000000 | (nib<<16) == 128+nib exactly; low nibble = even k
          const float lo = __builtin_bit_cast(float, 0x43000000u | ((qd & 0x0Fu) << 16));
          const float hi = __builtin_bit_cast(float, 0x43000000u | ((qd & 0xF0u) << 12));
          bfr[2 * i]     = (bf16)__builtin_fmaf(lo, c1, c0);
          bfr[2 * i + 1] = (bf16)__builtin_fmaf(hi, c1, c0);
        }
#pragma unroll
        for (int mt = 0; mt < 2; ++mt) {
          const bf16x8 af = *(const bf16x8*)(Ab + (mt * 16 + lr) * KK + kb_e + t * 128 + s * 32 + lg * 8);
          acc[mt] = __builtin_amdgcn_mfma_f32_16x16x32_bf16(af, bfr, acc[mt], 0, 0, 0);
        }
      }
    }
  }

  // ---- cross-wave k-reduction through LDS ----
  if (wv > 0) {
#pragma unroll
    for (int mt = 0; mt < 2; ++mt)
#pragma unroll
      for (int r = 0; r < 4; ++r)
        red[wv - 1][l][mt * 4 + r] = acc[mt][r];
  }
  __syncthreads();
  if (wv == 0) {
    // C/D layout (verified m89/m91 + round-5 PASS): reg r of lane l ->
    // C[row=(l>>4)*4+r][col=l&15]; row = m (A operand), col = n (B operand).
#pragma unroll
    for (int mt = 0; mt < 2; ++mt)
#pragma unroll
      for (int r = 0; r < 4; ++r) {
        float v = acc[mt][r];
#pragma unroll
        for (int w2 = 0; w2 < 3; ++w2) v += red[w2][l][mt * 4 + r];
        const int m = mt * 16 + lg * 4 + r;
        const int n = n0 + lr;
        out[m * NN + n] = v + bias[n];
      }
  }
}

extern "C" void kernel_launch(void* const* d_in, const int* in_sizes, int n_in,
                              void* d_out, int out_size, void* d_ws, size_t ws_size,
                              hipStream_t stream) {
  const float* A    = (const float*)d_in[0];
  const int*   qw   = (const int*)d_in[1];
  const float* sc   = (const float*)d_in[2];
  const float* zr   = (const float*)d_in[3];
  const float* bias = (const float*)d_in[4];
  float*       out  = (float*)d_out;
  bf16*        Ab   = (bf16*)d_ws;   // 0.5 MB of the (large) scratch pool

  aconv_kernel<<<dim3(MM * KK / (256 * 8)), dim3(256), 0, stream>>>(A, Ab);
  qgemm_kernel<<<dim3(NBLOCKS), dim3(256), 0, stream>>>(Ab, qw, sc, zr, bias, out);
}

// Round 9
// 692.654 us; speedup vs baseline: 1.0655x; 1.0084x over previous
//
#include <hip/hip_runtime.h>

// ---- problem constants ----
#define KK 8192
#define NN 28672
#define MM 32
#define NBLK 16                 // n-rows per block
#define NBLOCKS (NN / NBLK)     // 1792 = 7 blocks/CU on 256 CUs
#define WTILES 16               // 128-k tiles per wave: K / (4 waves * 128)

// HARNESS DTYPE CONTRACT: universe is {bf16, f32, int32}; reference fp16
// tensors arrive as FLOAT32. Verified round 5/7 (PASS).
// MODEL NOTE (round 7): dequant VALU = lane-ops/64 -> only ~10M wave-instr
// (~10us chip). qgemm is LATENCY-bound (~250us vs 75us floor), not VALU-bound.
typedef _Float16 h1;
typedef h1    h2 __attribute__((ext_vector_type(2)));
typedef h1    h8 __attribute__((ext_vector_type(8)));
typedef float floatx4 __attribute__((ext_vector_type(4)));

// A (32x8192 f32, 1MB) -> f16 (0.5MB) once per launch into d_ws.
// A was originally fp16 in the reference, so f32->f16 here is EXACT.
__global__ __launch_bounds__(256) void aconv_kernel(const float* __restrict__ A,
                                                    h1* __restrict__ Ah) {
  const int i = (blockIdx.x * 256 + threadIdx.x) * 8;
  const float4 fa = *(const float4*)(A + i);
  const float4 fb = *(const float4*)(A + i + 4);
  h8 o;
  o[0] = (h1)fa.x; o[1] = (h1)fa.y; o[2] = (h1)fa.z; o[3] = (h1)fa.w;
  o[4] = (h1)fb.x; o[5] = (h1)fb.y; o[6] = (h1)fb.z; o[7] = (h1)fb.w;
  *(h8*)(Ah + i) = o;
}

// 4 int32 (one byte each, 2 nibbles = 2 weights) -> 8 dequantized f16.
// Per int32: t=q|(q<<12); p=(t&0x000F000F)|0x64006400 -> f16 pair (1024+lo,1024+hi)
// EXACT; pk_add(-1024) -> (lo,hi) EXACT; w = e*s + (-z*s) packed. 4 VALU/int32.
__device__ __forceinline__ h8 dequant8(const uint4 v, const h2 spk, const h2 mzspk) {
  h8 w;
#pragma unroll
  for (int i = 0; i < 4; ++i) {
    const unsigned q = ((const unsigned*)&v)[i];
    const unsigned t = q | (q << 12);
    const unsigned p = (t & 0x000F000Fu) | 0x64006400u;
    const h2 e = __builtin_bit_cast(h2, p) + (h2){(h1)(-1024.f), (h1)(-1024.f)};
    const h2 wv = e * spk + mzspk;
    w[2 * i]     = wv.x;
    w[2 * i + 1] = wv.y;
  }
  return w;
}

// One block: 4 waves, 16 n-rows, full M=32. Wave wv owns k in [wv*2048, +2048).
// Per 128-k tile: 4 s-steps x 2 m-tiles of mfma 16x16x32 f16.
// k-bijection (same map for A and B frags): k = s*32 + lg*8 + elem, lg = lane>>4.
// B stream register-double-buffered one tile ahead (latency hiding).
__global__ __launch_bounds__(256, 4) void qgemm_kernel(
    const h1* __restrict__ Ah, const int* __restrict__ qw,
    const float* __restrict__ scales, const float* __restrict__ zeros,
    const float* __restrict__ bias, float* __restrict__ out) {
  __shared__ float red[3][64][8];   // 6 KB: waves 1-3 park partials

  const int tid = threadIdx.x;
  const int wv  = tid >> 6;
  const int l   = tid & 63;
  const int lr  = l & 15;   // n-row selector (B) / m-row selector with mt (A)
  const int lg  = l >> 4;   // k-chunk selector
  const int n0  = blockIdx.x * NBLK;

  const int kb_e = wv * 2048;   // element k base for this wave
  const int kb_i = wv * 1024;   // int32 k base (2 weights per int32)
  const int gb   = wv * WTILES; // first quant group of this wave's k-range

  // one base pointer for all 64 B-loads; per-load offsets are 13-bit immediates
  const int* qbase = qw + (n0 + lr) * 4096 + kb_i + lg * 4;
  // A base pointers (f16), one per m-tile
  const h1* abase0 = Ah + lr * KK + kb_e + lg * 8;
  const h1* abase1 = abase0 + 16 * KK;

  const float4* sp = (const float4*)(scales + (n0 + lr) * 64 + gb);
  const float4* zp = (const float4*)(zeros  + (n0 + lr) * 64 + gb);

  floatx4 acc[2];
  acc[0] = (floatx4){0.f, 0.f, 0.f, 0.f};
  acc[1] = (floatx4){0.f, 0.f, 0.f, 0.f};

  // prologue: tile 0's B into buffer 0
  uint4 b[2][4];
#pragma unroll
  for (int s = 0; s < 4; ++s) b[0][s] = *(const uint4*)(qbase + s * 16);

#pragma unroll
  for (int q4 = 0; q4 < 4; ++q4) {
    const float4 sv = sp[q4];
    const float4 zv = zp[q4];
#pragma unroll
    for (int u = 0; u < 4; ++u) {
      const int t = q4 * 4 + u;           // tile index, fully static
      // ---- prefetch next tile's B (register double-buffer) ----
      if (t + 1 < WTILES) {
#pragma unroll
        for (int s = 0; s < 4; ++s)
          b[(t + 1) & 1][s] = *(const uint4*)(qbase + (t + 1) * 64 + s * 16);
      }
      const float sf = (u == 0) ? sv.x : (u == 1) ? sv.y : (u == 2) ? sv.z : sv.w;
      const float zf = (u == 0) ? zv.x : (u == 1) ? zv.y : (u == 2) ? zv.z : zv.w;
      const h2 spk   = {(h1)sf, (h1)sf};
      const float mz = -zf * sf;
      const h2 mzspk = {(h1)mz, (h1)mz};

#pragma unroll
      for (int s = 0; s < 4; ++s) {
        const h8 bfr = dequant8(b[t & 1][s], spk, mzspk);
#pragma unroll
        for (int mt = 0; mt < 2; ++mt) {
          const h1* ap = (mt == 0 ? abase0 : abase1) + t * 128 + s * 32;
          const h8 af = *(const h8*)(ap);
          acc[mt] = __builtin_amdgcn_mfma_f32_16x16x32_f16(af, bfr, acc[mt], 0, 0, 0);
        }
      }
    }
  }

  // ---- cross-wave k-reduction through LDS ----
  if (wv > 0) {
#pragma unroll
    for (int mt = 0; mt < 2; ++mt)
#pragma unroll
      for (int r = 0; r < 4; ++r)
        red[wv - 1][l][mt * 4 + r] = acc[mt][r];
  }
  __syncthreads();
  if (wv == 0) {
    // C/D layout (verified m89/m91 + round-5/7 PASS): reg r of lane l ->
    // C[row=(l>>4)*4+r][col=l&15]; row = m (A operand), col = n (B operand).
#pragma unroll
    for (int mt = 0; mt < 2; ++mt)
#pragma unroll
      for (int r = 0; r < 4; ++r) {
        float v = acc[mt][r];
#pragma unroll
        for (int w2 = 0; w2 < 3; ++w2) v += red[w2][l][mt * 4 + r];
        const int m = mt * 16 + lg * 4 + r;
        const int n = n0 + lr;
        out[m * NN + n] = v + bias[n];
      }
  }
}

extern "C" void kernel_launch(void* const* d_in, const int* in_sizes, int n_in,
                              void* d_out, int out_size, void* d_ws, size_t ws_size,
                              hipStream_t stream) {
  const float* A    = (const float*)d_in[0];
  const int*   qw   = (const int*)d_in[1];
  const float* sc   = (const float*)d_in[2];
  const float* zr   = (const float*)d_in[3];
  const float* bias = (const float*)d_in[4];
  float*       out  = (float*)d_out;
  h1*          Ah   = (h1*)d_ws;   // 0.5 MB of scratch

  aconv_kernel<<<dim3(MM * KK / (256 * 8)), dim3(256), 0, stream>>>(A, Ah);
  qgemm_kernel<<<dim3(NBLOCKS), dim3(256), 0, stream>>>(Ah, qw, sc, zr, bias, out);
}